// Round 14
// baseline (34814.606 us; speedup 1.0000x reference)
//
#include <hip/hip_runtime.h>
#include <cmath>

#define TDEC 250
#define EPS_A 1e-6f

// ---------------- block groups ----------------
#define NB_GIC  64   // 64 blocks: 4bg x 16jg
#define NB_GA   128  // 16 blocks: 4bg x 4jg
#define NB_WH1  144  // 8 blocks
#define NB_WH2  152  // 8 blocks
#define NBLK    160

// ---------------- ws float offsets (flags in words 0..8191) ----------------
// MEGA flag words: 0=ctx, 1=hatt, 2=h1, 3=h2. helpers: word 0.
#define B_CTX(p)  (8192   + (p)*49152)   // [64][768]
#define B_HATT(p) (106496 + (p)*16384)   // [64][256]
#define B_H1(p)   (139264 + (p)*16384)
#define B_H2(p)   (172032 + (p)*16384)
#define B_GIC(p)  (204800 + (p)*49152)   // [64][768]
#define B_GH(p)   (303104 + (p)*49152)
#define B_GH1(p)  (401408 + (p)*49152)
#define B_GH2(p)  (499712 + (p)*49152)
#define ZERO_END  598016
#define CVT_OFF   598016                 // bf16 weight region (u16)

// bf16 weight offsets (u16 units)
#define OP1   0u        // p1w  [256][416] (rows padded 400->416)
#define OP2   106496u   // p2w  [128][256]
#define OAWI  139264u   // awi  [768][896]
#define OAWH  827392u   // awh  [768][256]
#define ODW   1024000u  // dWw  [128][256]
#define ODV   1056768u  // dVw  [168][128]
#define OLW   1078272u  // lw   [256][1024]
#define OG1I  1340416u  // g1wi [768][256]
#define OG2I  1537024u
#define OG1H  1733632u
#define OG2H  1930240u
#define OPR   2126848u  // prw  [400][256]

struct Prior { float v[11]; };

struct KArgs {
  const float *enc;
  const float *p1w,*p1b,*p2w,*p2b;
  const float *awi,*abi,*awh,*abh;
  const float *dWw,*dWb,*dVw,*dFw,*dUw,*dTw,*dTb,*dvw;
  const float *lw,*lb;
  const float *g1wi,*g1bi,*g1wh,*g1bh;
  const float *g2wi,*g2bi,*g2wh,*g2bh;
  const float *prw,*prb;
  float* ws; float* dout;
  Prior pr;
};

__device__ __forceinline__ float gld(const float* p) {
  return __uint_as_float(__hip_atomic_load((const unsigned*)p, __ATOMIC_RELAXED, __HIP_MEMORY_SCOPE_AGENT));
}
__device__ __forceinline__ void gst(float* p, float v) {
  __hip_atomic_store((unsigned*)p, __float_as_uint(v), __ATOMIC_RELAXED, __HIP_MEMORY_SCOPE_AGENT);
}
__device__ __forceinline__ float sigm(float x) { return 1.f / (1.f + expf(-x)); }

// bf16-pair dot: one uint4 = 8 bf16 weights vs 8 fp32 activations (two float4)
__device__ __forceinline__ float dot8(uint4 w, float4 x0, float4 x1) {
  float a;
  a = __uint_as_float(w.x << 16) * x0.x;
  a = fmaf(__uint_as_float(w.x & 0xffff0000u), x0.y, a);
  a = fmaf(__uint_as_float(w.y << 16),         x0.z, a);
  a = fmaf(__uint_as_float(w.y & 0xffff0000u), x0.w, a);
  a = fmaf(__uint_as_float(w.z << 16),         x1.x, a);
  a = fmaf(__uint_as_float(w.z & 0xffff0000u), x1.y, a);
  a = fmaf(__uint_as_float(w.w << 16),         x1.z, a);
  a = fmaf(__uint_as_float(w.w & 0xffff0000u), x1.w, a);
  return a;
}

__global__ __launch_bounds__(256) void k_init(float* ws) {
  int idx = blockIdx.x * 256 + threadIdx.x;
  for (int i = idx; i < ZERO_END; i += gridDim.x * 256) ws[i] = 0.f;
}

// ---------------- fp32 -> bf16 (RTNE) weight conversion ----------------
struct CvtSeg { const float* src; unsigned dst; unsigned n; };
struct CvtArgs { CvtSeg s[12]; };
__global__ __launch_bounds__(256) void k_cvt(CvtArgs c, unsigned short* wb) {
  // seg 0: p1w with row padding 400 -> 416
  for (unsigned i = blockIdx.x * 256 + threadIdx.x; i < 256u * 416u; i += gridDim.x * 256) {
    unsigned row = i / 416u, col = i - row * 416u;
    unsigned short v = 0;
    if (col < 400u) {
      unsigned u = __float_as_uint(c.s[0].src[row * 400u + col]);
      v = (unsigned short)((u + 0x7fffu + ((u >> 16) & 1u)) >> 16);
    }
    wb[OP1 + i] = v;
  }
  for (int seg = 1; seg < 12; ++seg) {
    const float* s = c.s[seg].src;
    unsigned short* d = wb + c.s[seg].dst;
    unsigned n = c.s[seg].n;
    for (unsigned i = blockIdx.x * 256 + threadIdx.x; i < n; i += gridDim.x * 256) {
      unsigned u = __float_as_uint(s[i]);
      d[i] = (unsigned short)((u + 0x7fffu + ((u >> 16) & 1u)) >> 16);
    }
  }
}

__device__ __forceinline__ void postw(unsigned* fl, int word, unsigned v) {
  asm volatile("s_waitcnt vmcnt(0)" ::: "memory");
  __syncthreads();
  if (threadIdx.x == 0)
    __hip_atomic_store(&fl[blockIdx.x * 32 + word], v, __ATOMIC_RELAXED, __HIP_MEMORY_SCOPE_AGENT);
}
template <int SLP>
__device__ __forceinline__ void pollge(unsigned* fl, int line, int word, unsigned v) {
  while (__hip_atomic_load(&fl[line * 32 + word], __ATOMIC_RELAXED, __HIP_MEMORY_SCOPE_AGENT) < v)
    __builtin_amdgcn_s_sleep(SLP);
}

// ---------------- the persistent decoder ----------------
__global__ __launch_bounds__(1024, 1) void k_decode(KArgs A) {
  __shared__ __align__(16) float sm[16640];
  float* ws = A.ws;
  unsigned* fl = (unsigned*)ws;
  const unsigned short* wb = (const unsigned short*)(ws + CVT_OFF);
  const int blk = blockIdx.x;
  const int tid = threadIdx.x;

  if (blk < 64) {
    // ========== MEGA: one block per batch row, the ENTIRE per-step chain ==========
    const int b = blk, bg = b >> 4;
    float* alpha = sm;            // 512
    float* hattl = sm + 512;      // 256
    float* h1l   = sm + 768;      // 256
    float* h2l   = sm + 1024;     // 256
    float* fr    = sm + 1280;     // 416
    float* ctxl  = sm + 1696;     // 768
    float* xl    = sm + 2464;     // 256
    float* x2l   = sm + 2720;     // 256
    float* x3l   = sm + 2976;     // 256
    float* sal   = sm + 3232;     // 544
    float* h1s   = sm + 3776;     // 256
    float* pre   = sm + 4032;     // 128
    float* sgi   = sm + 4160;     // 768
    float* sgh   = sm + 4928;     // 768
    float* t1    = sm + 5696;     // 128
    float* Gl    = sm + 5824;     // 176
    float* sdF   = sm + 6000;     // 176
    float* sdU   = sm + 6176;     // 1024
    float* sdT   = sm + 7200;     // 1024
    float* sdtb  = sm + 8224;     // 128
    float* sdv   = sm + 8352;     // 128
    float* es    = sm + 8480;     // 1024
    float* e     = sm + 9504;     // 512
    float* red   = sm + 10016;    // 16
    int*   wc    = (int*)(sm + 10032); // 8
    float* lv    = sm + 10040;    // 512
    short* li    = (short*)(sm + 10552); // 512 shorts

    // one-time init
    if (tid < 512) alpha[tid] = (tid == 0) ? 1.f : 0.f;
    if (tid < 256) { hattl[tid] = 0.f; h1l[tid] = 0.f; h2l[tid] = 0.f; }
    if (tid < 416) fr[tid] = 0.f;
    if (tid < 176) sdF[tid] = (tid < 168) ? A.dFw[tid] : 0.f;
    sdU[tid] = A.dUw[tid];
    sdT[tid] = A.dTw[tid];
    if (tid < 128) { sdtb[tid] = A.dTb[tid]; sdv[tid] = A.dvw[tid]; }
    __syncthreads();

    for (int t = 0; t < TDEC; ++t) {
      const int p = t & 1;
      // S0: alpha -> padded sal
      if (tid < 544) { int sg = tid - 10; sal[tid] = (sg >= 0 && sg < 512) ? alpha[sg] : 0.f; }
      __syncthreads();
      // S1: prenet L1 (256 j x 4 parts, constant 13-iter)
      {
        int j = tid >> 2, part = tid & 3;
        const uint4* wr = (const uint4*)(wb + OP1 + (size_t)j * 416) + part * 13;
        const float4* xr = (const float4*)fr + part * 26;
        float a = 0.f;
#pragma unroll
        for (int k4 = 0; k4 < 13; ++k4) a += dot8(wr[k4], xr[2*k4], xr[2*k4+1]);
        a += __shfl_xor(a, 1); a += __shfl_xor(a, 2);
        if (part == 0) h1s[j] = fmaxf(a + A.p1b[j], 0.f);
      }
      __syncthreads();
      // S2: prenet L2 (128 j x 8 parts)
      {
        int j = tid >> 3, part = tid & 7;
        const uint4* wr = (const uint4*)(wb + OP2 + (size_t)j * 256) + part * 4;
        const float4* xr = (const float4*)h1s + part * 8;
        float a = 0.f;
#pragma unroll
        for (int k4 = 0; k4 < 4; ++k4) a += dot8(wr[k4], xr[2*k4], xr[2*k4+1]);
        a += __shfl_xor(a, 1); a += __shfl_xor(a, 2); a += __shfl_xor(a, 4);
        if (part == 0) pre[j] = fmaxf(a + A.p2b[j], 0.f);
      }
      __syncthreads();
      // S3: gip (awi pre-slice) || poll GIC(16) + GA(4)
      float gipre = 0.f;
      if (tid < 768) {
        const uint4* wr = (const uint4*)(wb + OAWI + (size_t)tid * 896 + 768);
        const float4* xr = (const float4*)pre;
        float a = 0.f;
#pragma unroll
        for (int k4 = 0; k4 < 16; ++k4) a += dot8(wr[k4], xr[2*k4], xr[2*k4+1]);
        gipre = a;
      } else if (tid < 784) {
        pollge<1>(fl, NB_GIC + bg * 16 + (tid - 768), 0, (unsigned)(t + 1));
      } else if (tid < 788) {
        pollge<1>(fl, NB_GA + bg * 4 + (tid - 784), 0, (unsigned)(t + 1));
      }
      __syncthreads();
      // S4: gate pre-activations
      if (tid < 768) {
        sgi[tid] = gipre + gld(ws + B_GIC(p) + b * 768 + tid) + A.abi[tid];
        sgh[tid] = gld(ws + B_GH(p) + b * 768 + tid) + A.abh[tid];
      }
      __syncthreads();
      // S5: att-GRU combine -> hatt
      if (tid < 256) {
        float r = sigm(sgi[tid] + sgh[tid]);
        float z = sigm(sgi[256 + tid] + sgh[256 + tid]);
        float n = tanhf(sgi[512 + tid] + r * sgh[512 + tid]);
        float hnew = (1.f - z) * n + z * hattl[tid];
        hattl[tid] = hnew;
        gst(ws + B_HATT(p) + b * 256 + tid, hnew);
      }
      postw(fl, 1, (unsigned)(t + 1));
      // S6: t1 = tanh(dW @ hatt + dWb)
      {
        int j = tid >> 3, part = tid & 7;
        const uint4* wr = (const uint4*)(wb + ODW + (size_t)j * 256) + part * 4;
        const float4* xr = (const float4*)hattl + part * 8;
        float a = 0.f;
#pragma unroll
        for (int k4 = 0; k4 < 4; ++k4) a += dot8(wr[k4], xr[2*k4], xr[2*k4+1]);
        a += __shfl_xor(a, 1); a += __shfl_xor(a, 2); a += __shfl_xor(a, 4);
        if (part == 0) t1[j] = tanhf(a + A.dWb[j]);
      }
      __syncthreads();
      // S7: G = dV @ t1 (bf16 stream)
      if (tid < 168) {
        const uint4* wr = (const uint4*)(wb + ODV + (size_t)tid * 128);
        const float4* xr = (const float4*)t1;
        float a = 0.f;
#pragma unroll
        for (int k4 = 0; k4 < 16; ++k4) a += dot8(wr[k4], xr[2*k4], xr[2*k4+1]);
        Gl[tid] = a;
      }
      __syncthreads();
      // S8: static+dynamic conv fused with energy MLP
      {
        int sl = tid >> 1, half = tid & 1;
        float f0[8], g0[8];
#pragma unroll
        for (int q = 0; q < 8; ++q) {
          float fa = 0.f, ga = 0.f;
#pragma unroll
          for (int k = 0; k < 21; ++k) {
            float a = sal[sl + k];
            fa = fmaf(sdF[q * 21 + k], a, fa);
            ga = fmaf(Gl[q * 21 + k], a, ga);
          }
          f0[q] = fa; g0[q] = ga;
        }
        float acc = 0.f;
        for (int cc = half * 64; cc < half * 64 + 64; ++cc) {
          float a = sdtb[cc];
#pragma unroll
          for (int q = 0; q < 8; ++q)
            a = fmaf(sdU[cc * 8 + q], f0[q], fmaf(sdT[cc * 8 + q], g0[q], a));
          acc = fmaf(sdv[cc], tanhf(a), acc);
        }
        es[sl * 2 + half] = acc;
      }
      __syncthreads();
      // S9a: e = mlp + log(prior)
      if (tid < 512) {
        float pr = 0.f;
#pragma unroll
        for (int k = 0; k < 11; ++k) pr = fmaf(A.pr.v[k], sal[tid + k], pr);
        e[tid] = es[tid * 2] + es[tid * 2 + 1] + logf(fmaxf(pr, 1e-6f));
      }
      __syncthreads();
      // S9b: softmax + compaction + sparse ctx (enc bypass)
      {
        int lane = tid & 63, wv = tid >> 6;
        float e0 = (tid < 512) ? e[tid] : -1e30f;
        float m = e0;
        for (int o = 32; o; o >>= 1) m = fmaxf(m, __shfl_xor(m, o));
        if (lane == 0) red[wv] = m;
        __syncthreads();
        m = red[0];
        for (int w = 1; w < 8; ++w) m = fmaxf(m, red[w]);
        float p0 = (tid < 512) ? expf(e0 - m) : 0.f;
        float s = p0;
        for (int o = 32; o; o >>= 1) s += __shfl_xor(s, o);
        __syncthreads();
        if (lane == 0) red[wv] = s;
        __syncthreads();
        float tot = red[0];
        for (int w = 1; w < 8; ++w) tot += red[w];
        float inv = 1.f / tot;
        float a0 = p0 * inv;
        if (tid < 512) alpha[tid] = a0;
        unsigned long long mk = __ballot(tid < 512 && a0 > EPS_A);
        if (lane == 0 && wv < 8) wc[wv] = (int)__popcll(mk);
        __syncthreads();
        int base = 0;
        for (int w = 0; w < wv && w < 8; ++w) base += wc[w];
        int n = 0;
        for (int w = 0; w < 8; ++w) n += wc[w];
        unsigned long long below = (1ull << lane) - 1ull;
        if (tid < 512 && a0 > EPS_A) {
          int pp = base + (int)__popcll(mk & below);
          li[pp] = (short)tid; lv[pp] = a0;
        }
        __syncthreads();
        const float* encb = A.enc + (size_t)b * 512 * 768;
        if (tid < 768) {
          float acc = 0.f;
          int i = 0;
          for (; i + 4 <= n; i += 4) {
            float v0 = gld(encb + (size_t)li[i] * 768 + tid);
            float v1 = gld(encb + (size_t)li[i+1] * 768 + tid);
            float v2 = gld(encb + (size_t)li[i+2] * 768 + tid);
            float v3 = gld(encb + (size_t)li[i+3] * 768 + tid);
            acc = fmaf(lv[i],v0, fmaf(lv[i+1],v1, fmaf(lv[i+2],v2, fmaf(lv[i+3],v3, acc))));
          }
          for (; i < n; ++i) acc = fmaf(lv[i], gld(encb + (size_t)li[i] * 768 + tid), acc);
          ctxl[tid] = acc;
          gst(ws + B_CTX(p) + b * 768 + tid, acc);
        }
      }
      postw(fl, 0, (unsigned)(t + 1));
      // S10: x = lw @ [ctx; hatt] + lb
      {
        int j = tid >> 2, part = tid & 3;
        const uint4* wr = (const uint4*)(wb + OLW + (size_t)j * 1024) + part * 32;
        const float4* xr = (part < 3) ? ((const float4*)ctxl + part * 64) : (const float4*)hattl;
        float a = 0.f;
#pragma unroll 16
        for (int k4 = 0; k4 < 32; ++k4) a += dot8(wr[k4], xr[2*k4], xr[2*k4+1]);
        a += __shfl_xor(a, 1); a += __shfl_xor(a, 2);
        if (part == 0) xl[j] = a + A.lb[j];
      }
      __syncthreads();
      // S11: GRU1 (g1wi local; gh1 from WH1 helper)
      {
        float giv = 0.f;
        if (tid < 768) {
          const uint4* wr = (const uint4*)(wb + OG1I + (size_t)tid * 256);
          const float4* xr = (const float4*)xl;
          float a = 0.f;
#pragma unroll 16
          for (int k4 = 0; k4 < 32; ++k4) a += dot8(wr[k4], xr[2*k4], xr[2*k4+1]);
          giv = a;
        } else if (tid < 776) {
          pollge<1>(fl, NB_WH1 + (tid - 768), 0, (unsigned)(t + 1));
        }
        __syncthreads();
        if (tid < 768) {
          sgi[tid] = giv + A.g1bi[tid];
          sgh[tid] = gld(ws + B_GH1(p) + b * 768 + tid);   // helper added g1bh
        }
        __syncthreads();
        if (tid < 256) {
          float r = sigm(sgi[tid] + sgh[tid]);
          float z = sigm(sgi[256 + tid] + sgh[256 + tid]);
          float n = tanhf(sgi[512 + tid] + r * sgh[512 + tid]);
          float hnew = (1.f - z) * n + z * h1l[tid];
          h1l[tid] = hnew;
          gst(ws + B_H1(p) + b * 256 + tid, hnew);
          x2l[tid] = xl[tid] + hnew;
        }
        postw(fl, 2, (unsigned)(t + 1));
      }
      // S12: GRU2
      {
        float giv = 0.f;
        if (tid < 768) {
          const uint4* wr = (const uint4*)(wb + OG2I + (size_t)tid * 256);
          const float4* xr = (const float4*)x2l;
          float a = 0.f;
#pragma unroll 16
          for (int k4 = 0; k4 < 32; ++k4) a += dot8(wr[k4], xr[2*k4], xr[2*k4+1]);
          giv = a;
        } else if (tid < 776) {
          pollge<1>(fl, NB_WH2 + (tid - 768), 0, (unsigned)(t + 1));
        }
        __syncthreads();
        if (tid < 768) {
          sgi[tid] = giv + A.g2bi[tid];
          sgh[tid] = gld(ws + B_GH2(p) + b * 768 + tid);
        }
        __syncthreads();
        if (tid < 256) {
          float r = sigm(sgi[tid] + sgh[tid]);
          float z = sigm(sgi[256 + tid] + sgh[256 + tid]);
          float n = tanhf(sgi[512 + tid] + r * sgh[512 + tid]);
          float hnew = (1.f - z) * n + z * h2l[tid];
          h2l[tid] = hnew;
          gst(ws + B_H2(p) + b * 256 + tid, hnew);
          x3l[tid] = x2l[tid] + hnew;
        }
        postw(fl, 3, (unsigned)(t + 1));
      }
      // S13: proj -> fr (next frame) + dout (bypass)
      if (tid < 800) {
        int j = tid >> 1, part = tid & 1;
        const uint4* wr = (const uint4*)(wb + OPR + (size_t)j * 256) + part * 16;
        const float4* xr = (const float4*)x3l + part * 32;
        float a = 0.f;
#pragma unroll 16
        for (int k4 = 0; k4 < 16; ++k4) a += dot8(wr[k4], xr[2*k4], xr[2*k4+1]);
        a += __shfl_xor(a, 1);
        if (part == 0) {
          float v = a + A.prb[j];
          fr[j] = v;
          gst(A.dout + (size_t)b * 100000 + (j / 5) * 1250 + t * 5 + (j % 5), v);
        }
      }
      __syncthreads();
    }
  } else if (blk < NB_GA) {
    // ---- GIC: gic(t) = awi[:, :768] @ ctx(t-1)  (shadow) ----
    int rb = blk - NB_GIC, bg = rb >> 4, jg = rb & 15;
    int B = bg * 16, R0 = jg * 48;
    float* cl = sm;  // [16][772]
    for (int t = 0; t < TDEC; ++t) {
      const int p = t & 1;
      if (tid < 16) pollge<4>(fl, bg * 16 + tid, 0, (unsigned)t);
      __syncthreads();
      for (int idx = tid; idx < 12288; idx += 1024) {
        int bb = idx / 768, k = idx - bb * 768;
        cl[bb * 772 + k] = gld(ws + B_CTX(p ^ 1) + (B + bb) * 768 + k);
      }
      __syncthreads();
      if (tid < 768) {
        int rr = tid >> 4, bb = tid & 15;
        int row = R0 + rr;
        const uint4* wr = (const uint4*)(wb + OAWI + (size_t)row * 896);
        const float4* xr = (const float4*)(cl + bb * 772);
        float a = 0.f;
#pragma unroll 16
        for (int k4 = 0; k4 < 96; ++k4) a += dot8(wr[k4], xr[2*k4], xr[2*k4+1]);
        gst(ws + B_GIC(p) + (B + bb) * 768 + row, a);
      }
      postw(fl, 0, (unsigned)(t + 1));
    }
  } else if (blk < NB_WH1) {
    // ---- GA: gh(t) = awh @ hatt(t-1)  (shadow) ----
    int rb = blk - NB_GA, bg = rb >> 2, jg = rb & 3;
    int B = bg * 16, R0 = jg * 192;
    float* hl = sm;  // [16][260]
    for (int t = 0; t < TDEC; ++t) {
      const int p = t & 1;
      if (tid < 16) pollge<4>(fl, bg * 16 + tid, 1, (unsigned)t);
      __syncthreads();
      for (int idx = tid; idx < 4096; idx += 1024) {
        int bb = idx >> 8, k = idx & 255;
        hl[bb * 260 + k] = gld(ws + B_HATT(p ^ 1) + (B + bb) * 256 + k);
      }
      __syncthreads();
#pragma unroll
      for (int pass = 0; pass < 3; ++pass) {
        int rr = pass * 64 + (tid >> 4), bb = tid & 15;
        int row = R0 + rr;
        const uint4* wr = (const uint4*)(wb + OAWH + (size_t)row * 256);
        const float4* xr = (const float4*)(hl + bb * 260);
        float a = 0.f;
#pragma unroll 16
        for (int k4 = 0; k4 < 32; ++k4) a += dot8(wr[k4], xr[2*k4], xr[2*k4+1]);
        gst(ws + B_GH(p) + (B + bb) * 768 + row, a);
      }
      postw(fl, 0, (unsigned)(t + 1));
    }
  } else {
    // ---- WH1/WH2: gh{1,2}(t) = g{1,2}wh @ h{1,2}(t-1), all 64 b  (shadow) ----
    const int isW2 = (blk >= NB_WH2);
    const int w = blk - (isW2 ? NB_WH2 : NB_WH1);
    const unsigned OW = isW2 ? OG2H : OG1H;
    const float* bh = isW2 ? A.g2bh : A.g1bh;
    const int hOff0  = isW2 ? B_H2(0)  : B_H1(0);
    const int ghOff0 = isW2 ? B_GH2(0) : B_GH1(0);
    const int word = isW2 ? 3 : 2;
    const int R0 = w * 96;
    float* hl = sm;  // [64][260]
    for (int t = 0; t < TDEC; ++t) {
      const int p = t & 1;
      if (tid < 64) pollge<4>(fl, tid, word, (unsigned)t);
      __syncthreads();
      for (int idx = tid; idx < 16384; idx += 1024) {
        int bb = idx >> 8, k = idx & 255;
        hl[bb * 260 + k] = gld(ws + hOff0 + (p ^ 1) * 16384 + bb * 256 + k);
      }
      __syncthreads();
#pragma unroll
      for (int pass = 0; pass < 6; ++pass) {
        int o = pass * 1024 + tid;
        int bb = o & 63, lr = o >> 6;
        int row = R0 + lr;
        const uint4* wr = (const uint4*)(wb + OW + (size_t)row * 256);
        const float4* xr = (const float4*)(hl + bb * 260);
        float a = 0.f;
#pragma unroll 16
        for (int k4 = 0; k4 < 32; ++k4) a += dot8(wr[k4], xr[2*k4], xr[2*k4+1]);
        gst(ws + ghOff0 + p * 49152 + bb * 768 + row, a + bh[row]);
      }
      postw(fl, 0, (unsigned)(t + 1));
    }
  }
}

// ---------------- host ----------------
extern "C" void kernel_launch(void* const* d_in, const int* in_sizes, int n_in,
                              void* d_out, int out_size, void* d_ws, size_t ws_size,
                              hipStream_t stream) {
  (void)in_sizes; (void)n_in; (void)out_size; (void)ws_size;
  KArgs A;
  A.enc  = (const float*)d_in[0];
  A.p1w  = (const float*)d_in[1];  A.p1b  = (const float*)d_in[2];
  A.p2w  = (const float*)d_in[3];  A.p2b  = (const float*)d_in[4];
  A.awi  = (const float*)d_in[5];  A.abi  = (const float*)d_in[6];
  A.awh  = (const float*)d_in[7];  A.abh  = (const float*)d_in[8];
  A.dWw  = (const float*)d_in[9];  A.dWb  = (const float*)d_in[10];
  A.dVw  = (const float*)d_in[11]; A.dFw  = (const float*)d_in[12];
  A.dUw  = (const float*)d_in[13]; A.dTw  = (const float*)d_in[14];
  A.dTb  = (const float*)d_in[15]; A.dvw  = (const float*)d_in[16];
  A.lw   = (const float*)d_in[17]; A.lb   = (const float*)d_in[18];
  A.g1wi = (const float*)d_in[19]; A.g1bi = (const float*)d_in[20];
  A.g1wh = (const float*)d_in[21]; A.g1bh = (const float*)d_in[22];
  A.g2wi = (const float*)d_in[23]; A.g2bi = (const float*)d_in[24];
  A.g2wh = (const float*)d_in[25]; A.g2bh = (const float*)d_in[26];
  A.prw  = (const float*)d_in[27]; A.prb  = (const float*)d_in[28];
  A.ws   = (float*)d_ws;
  A.dout = (float*)d_out;

  // beta-binomial prior pmf (n=10, a=0.1, b=0.9), flipped
  {
    double aP = 0.1, bP = 0.9;
    double logB0 = lgamma(aP) + lgamma(bP) - lgamma(aP + bP);
    double pm[11];
    for (int k = 0; k <= 10; ++k) {
      double logC = lgamma(11.0) - lgamma(k + 1.0) - lgamma(11.0 - k);
      double logBt = lgamma(k + aP) + lgamma(10.0 - k + bP) - lgamma(10.0 + aP + bP);
      pm[k] = exp(logC + logBt - logB0);
    }
    for (int k = 0; k < 11; ++k) A.pr.v[k] = (float)pm[10 - k];
  }

  CvtArgs C;
  C.s[0]  = {A.p1w,  OP1,  106496u};   // padded inside k_cvt
  C.s[1]  = {A.p2w,  OP2,  32768u};
  C.s[2]  = {A.awi,  OAWI, 688128u};
  C.s[3]  = {A.awh,  OAWH, 196608u};
  C.s[4]  = {A.dWw,  ODW,  32768u};
  C.s[5]  = {A.dVw,  ODV,  21504u};
  C.s[6]  = {A.lw,   OLW,  262144u};
  C.s[7]  = {A.g1wi, OG1I, 196608u};
  C.s[8]  = {A.g2wi, OG2I, 196608u};
  C.s[9]  = {A.g1wh, OG1H, 196608u};
  C.s[10] = {A.g2wh, OG2H, 196608u};
  C.s[11] = {A.prw,  OPR,  102400u};

  k_init<<<256, 256, 0, stream>>>((float*)d_ws);
  k_cvt<<<256, 256, 0, stream>>>(C, (unsigned short*)((float*)d_ws + CVT_OFF));
  k_decode<<<NBLK, 1024, 0, stream>>>(A);
}

// Round 15
// 29673.633 us; speedup vs baseline: 1.1733x; 1.1733x over previous
//
#include <hip/hip_runtime.h>
#include <cmath>

#define TDEC 250
#define EPS_A 1e-6f

// ---------------- block groups ----------------
#define NB_GIC  64   // 64 blocks: 4bg x 16jg
#define NB_GA   128  // 16 blocks: 4bg x 4jg
#define NB_WH1  144  // 8 blocks
#define NB_WH2  152  // 8 blocks
#define NBLK    160

// ---------------- ws float offsets (flags in words 0..8191) ----------------
// MEGA flag words: 0=ctx, 1=hatt, 2=h1, 3=h2. helpers: word 0.
#define B_CTX(p)  (8192   + (p)*49152)   // [64][768]
#define B_HATT(p) (106496 + (p)*16384)   // [64][256]
#define B_H1(p)   (139264 + (p)*16384)
#define B_H2(p)   (172032 + (p)*16384)
#define B_GIC(p)  (204800 + (p)*49152)   // [64][768]
#define B_GH(p)   (303104 + (p)*49152)
#define B_GH1(p)  (401408 + (p)*49152)
#define B_GH2(p)  (499712 + (p)*49152)
#define ZERO_END  598016
#define CVT_OFF   598016                 // bf16 weight region (u16)

// bf16 weight offsets (u16 units)
// k8-interleaved [K/8][N][8] region (MEGA GEMVs):
#define OP1    0u        // p1w  N=256 K=416(pad)
#define OP2    106496u   // p2w  N=128 K=256
#define OAWIP  139264u   // awi[:,768:896] N=768 K=128
#define ODW    237568u   // dWw  N=128 K=256
#define ODV    270336u   // dVw  N=168 K=128
#define OLW    291840u   // lw   N=256 K=1024
#define OG1I   553984u   // g1wi N=768 K=256
#define OG2I   750592u
#define OPR    947200u   // prw  N=400 K=256
// row-major region (helpers):
#define OAWI   1049600u  // awi  [768][896]
#define OAWH   1737728u  // awh  [768][256]
#define OG1H   1934336u
#define OG2H   2130944u

struct Prior { float v[11]; };

struct KArgs {
  const float *enc;
  const float *p1w,*p1b,*p2w,*p2b;
  const float *awi,*abi,*awh,*abh;
  const float *dWw,*dWb,*dVw,*dFw,*dUw,*dTw,*dTb,*dvw;
  const float *lw,*lb;
  const float *g1wi,*g1bi,*g1wh,*g1bh;
  const float *g2wi,*g2bi,*g2wh,*g2bh;
  const float *prw,*prb;
  float* ws; float* dout;
  Prior pr;
};

__device__ __forceinline__ float gld(const float* p) {
  return __uint_as_float(__hip_atomic_load((const unsigned*)p, __ATOMIC_RELAXED, __HIP_MEMORY_SCOPE_AGENT));
}
__device__ __forceinline__ void gst(float* p, float v) {
  __hip_atomic_store((unsigned*)p, __float_as_uint(v), __ATOMIC_RELAXED, __HIP_MEMORY_SCOPE_AGENT);
}
__device__ __forceinline__ float sigm(float x) { return 1.f / (1.f + expf(-x)); }

// bf16-pair dot: one uint4 = 8 bf16 weights (k..k+7) vs 8 fp32 activations
__device__ __forceinline__ float dot8(uint4 w, float4 x0, float4 x1) {
  float a;
  a = __uint_as_float(w.x << 16) * x0.x;
  a = fmaf(__uint_as_float(w.x & 0xffff0000u), x0.y, a);
  a = fmaf(__uint_as_float(w.y << 16),         x0.z, a);
  a = fmaf(__uint_as_float(w.y & 0xffff0000u), x0.w, a);
  a = fmaf(__uint_as_float(w.z << 16),         x1.x, a);
  a = fmaf(__uint_as_float(w.z & 0xffff0000u), x1.y, a);
  a = fmaf(__uint_as_float(w.w << 16),         x1.z, a);
  a = fmaf(__uint_as_float(w.w & 0xffff0000u), x1.w, a);
  return a;
}

__global__ __launch_bounds__(256) void k_init(float* ws) {
  int idx = blockIdx.x * 256 + threadIdx.x;
  for (int i = idx; i < ZERO_END; i += gridDim.x * 256) ws[i] = 0.f;
}

// ---------------- fp32 -> bf16 weight conversion (row-major or k8-interleaved) ----
struct CvtSeg { const float* src; unsigned dst; unsigned N, K, KP, sstr, soff, mode; };
struct CvtArgs { CvtSeg s[13]; };
__global__ __launch_bounds__(256) void k_cvt(CvtArgs c, unsigned short* wb) {
  for (int seg = 0; seg < 13; ++seg) {
    CvtSeg sg = c.s[seg];
    unsigned short* d = wb + sg.dst;
    unsigned tot = sg.N * sg.KP;
    for (unsigned i = blockIdx.x * 256 + threadIdx.x; i < tot; i += gridDim.x * 256) {
      if (sg.mode == 0) {
        unsigned u = __float_as_uint(sg.src[i]);
        d[i] = (unsigned short)((u + 0x7fffu + ((u >> 16) & 1u)) >> 16);
      } else {
        unsigned n = i / sg.KP, k = i - n * sg.KP;
        unsigned short v = 0;
        if (k < sg.K) {
          unsigned u = __float_as_uint(sg.src[(size_t)n * sg.sstr + sg.soff + k]);
          v = (unsigned short)((u + 0x7fffu + ((u >> 16) & 1u)) >> 16);
        }
        d[(k >> 3) * (sg.N * 8) + n * 8 + (k & 7)] = v;
      }
    }
  }
}

__device__ __forceinline__ void postw(unsigned* fl, int word, unsigned v) {
  asm volatile("s_waitcnt vmcnt(0)" ::: "memory");
  __syncthreads();
  if (threadIdx.x == 0)
    __hip_atomic_store(&fl[blockIdx.x * 32 + word], v, __ATOMIC_RELAXED, __HIP_MEMORY_SCOPE_AGENT);
}
template <int SLP>
__device__ __forceinline__ void pollge(unsigned* fl, int line, int word, unsigned v) {
  while (__hip_atomic_load(&fl[line * 32 + word], __ATOMIC_RELAXED, __HIP_MEMORY_SCOPE_AGENT) < v)
    __builtin_amdgcn_s_sleep(SLP);
}

// ---------------- the persistent decoder ----------------
__global__ __launch_bounds__(1024, 1) void k_decode(KArgs A) {
  __shared__ __align__(16) float sm[16640];
  float* ws = A.ws;
  unsigned* fl = (unsigned*)ws;
  const unsigned short* wb = (const unsigned short*)(ws + CVT_OFF);
  const int blk = blockIdx.x;
  const int tid = threadIdx.x;

  if (blk < 64) {
    // ========== MEGA: one block per batch row, entire per-step chain; k8 GEMVs ==========
    const int b = blk, bg = b >> 4;
    float* alpha = sm;            // 512
    float* hattl = sm + 512;      // 256
    float* h1l   = sm + 768;      // 256
    float* h2l   = sm + 1024;     // 256
    float* fr    = sm + 1280;     // 416
    float* xcat  = sm + 1696;     // 1032 (ctx 768 | hatt 256)
    float* xl    = sm + 2728;     // 256
    float* x2l   = sm + 2984;     // 256
    float* x3l   = sm + 3240;     // 256
    float* sal   = sm + 3496;     // 544
    float* h1s   = sm + 4040;     // 256
    float* pre   = sm + 4296;     // 128
    float* sgi   = sm + 4424;     // 768
    float* sgh   = sm + 5192;     // 768
    float* t1    = sm + 5960;     // 128
    float* Gl    = sm + 6088;     // 176
    float* sdF   = sm + 6264;     // 176
    float* sdU   = sm + 6440;     // 1024
    float* sdT   = sm + 7464;     // 1024
    float* sdtb  = sm + 8488;     // 128
    float* sdv   = sm + 8616;     // 128
    float* es    = sm + 8744;     // 1024
    float* e     = sm + 9768;     // 512
    float* red   = sm + 10280;    // 16
    int*   wc    = (int*)(sm + 10296); // 8
    float* lv    = sm + 10304;    // 512
    short* li    = (short*)(sm + 10816); // 512 shorts
    float* pt    = sm + 11072;    // 1056 partials

    if (tid < 512) alpha[tid] = (tid == 0) ? 1.f : 0.f;
    if (tid < 256) { hattl[tid] = 0.f; h1l[tid] = 0.f; h2l[tid] = 0.f; xcat[768 + tid] = 0.f; }
    if (tid < 416) fr[tid] = 0.f;
    if (tid < 176) sdF[tid] = (tid < 168) ? A.dFw[tid] : 0.f;
    sdU[tid] = A.dUw[tid];
    sdT[tid] = A.dTw[tid];
    if (tid < 128) { sdtb[tid] = A.dTb[tid]; sdv[tid] = A.dvw[tid]; }
    __syncthreads();

    for (int t = 0; t < TDEC; ++t) {
      const int p = t & 1;
      // S0: alpha -> padded sal
      if (tid < 544) { int sg = tid - 10; sal[tid] = (sg >= 0 && sg < 512) ? alpha[sg] : 0.f; }
      __syncthreads();
      // S1: prenet L1  N=256 K=416, 4 parts x 13 groups
      {
        int part = tid >> 8, j = tid & 255;
        const float4* xr = (const float4*)fr;
        float a = 0.f;
#pragma unroll
        for (int g = 0; g < 13; ++g) {
          int gg = part * 13 + g;
          uint4 w = *(const uint4*)(wb + OP1 + (size_t)gg * 2048 + j * 8);
          a += dot8(w, xr[gg * 2], xr[gg * 2 + 1]);
        }
        pt[part * 260 + j] = a;
      }
      __syncthreads();
      if (tid < 256) h1s[tid] = fmaxf(pt[tid] + pt[260 + tid] + pt[520 + tid] + pt[780 + tid] + A.p1b[tid], 0.f);
      __syncthreads();
      // S2: prenet L2  N=128 K=256, 8 parts x 4 groups
      {
        int part = tid >> 7, j = tid & 127;
        const float4* xr = (const float4*)h1s;
        float a = 0.f;
#pragma unroll
        for (int g = 0; g < 4; ++g) {
          int gg = part * 4 + g;
          uint4 w = *(const uint4*)(wb + OP2 + (size_t)gg * 1024 + j * 8);
          a += dot8(w, xr[gg * 2], xr[gg * 2 + 1]);
        }
        pt[part * 132 + j] = a;
      }
      __syncthreads();
      if (tid < 128) {
        float a = A.p2b[tid];
#pragma unroll
        for (int q = 0; q < 8; ++q) a += pt[q * 132 + tid];
        pre[tid] = fmaxf(a, 0.f);
      }
      __syncthreads();
      // S3: gip = awi[:,768:] @ pre  (N=768 K=128) || poll GIC + GA
      float gipre = 0.f;
      if (tid < 768) {
        const float4* xr = (const float4*)pre;
        float a = 0.f;
#pragma unroll
        for (int g = 0; g < 16; ++g) {
          uint4 w = *(const uint4*)(wb + OAWIP + (size_t)g * 6144 + tid * 8);
          a += dot8(w, xr[g * 2], xr[g * 2 + 1]);
        }
        gipre = a;
      } else if (tid < 784) {
        pollge<1>(fl, NB_GIC + bg * 16 + (tid - 768), 0, (unsigned)(t + 1));
      } else if (tid < 788) {
        pollge<1>(fl, NB_GA + bg * 4 + (tid - 784), 0, (unsigned)(t + 1));
      }
      __syncthreads();
      // S4: gate pre-activations
      if (tid < 768) {
        sgi[tid] = gipre + gld(ws + B_GIC(p) + b * 768 + tid) + A.abi[tid];
        sgh[tid] = gld(ws + B_GH(p) + b * 768 + tid) + A.abh[tid];
      }
      __syncthreads();
      // S5: att-GRU combine -> hatt
      if (tid < 256) {
        float r = sigm(sgi[tid] + sgh[tid]);
        float z = sigm(sgi[256 + tid] + sgh[256 + tid]);
        float n = tanhf(sgi[512 + tid] + r * sgh[512 + tid]);
        float hnew = (1.f - z) * n + z * hattl[tid];
        hattl[tid] = hnew;
        xcat[768 + tid] = hnew;
        gst(ws + B_HATT(p) + b * 256 + tid, hnew);
      }
      postw(fl, 1, (unsigned)(t + 1));
      // S6: t1 = tanh(dW @ hatt + dWb)  N=128 K=256
      {
        int part = tid >> 7, j = tid & 127;
        const float4* xr = (const float4*)hattl;
        float a = 0.f;
#pragma unroll
        for (int g = 0; g < 4; ++g) {
          int gg = part * 4 + g;
          uint4 w = *(const uint4*)(wb + ODW + (size_t)gg * 1024 + j * 8);
          a += dot8(w, xr[gg * 2], xr[gg * 2 + 1]);
        }
        pt[part * 132 + j] = a;
      }
      __syncthreads();
      if (tid < 128) {
        float a = A.dWb[tid];
#pragma unroll
        for (int q = 0; q < 8; ++q) a += pt[q * 132 + tid];
        t1[tid] = tanhf(a);
      }
      __syncthreads();
      // S7: G = dV @ t1  N=168 K=128, 4 parts x 4 groups (672 threads)
      if (tid < 672) {
        int part = tid / 168, j = tid - part * 168;
        const float4* xr = (const float4*)t1;
        float a = 0.f;
#pragma unroll
        for (int g = 0; g < 4; ++g) {
          int gg = part * 4 + g;
          uint4 w = *(const uint4*)(wb + ODV + (size_t)gg * 1344 + j * 8);
          a += dot8(w, xr[gg * 2], xr[gg * 2 + 1]);
        }
        pt[part * 172 + j] = a;
      }
      __syncthreads();
      if (tid < 168) Gl[tid] = pt[tid] + pt[172 + tid] + pt[344 + tid] + pt[516 + tid];
      __syncthreads();
      // S8: static+dynamic conv fused with energy MLP
      {
        int sl = tid >> 1, half = tid & 1;
        float f0[8], g0[8];
#pragma unroll
        for (int q = 0; q < 8; ++q) {
          float fa = 0.f, ga = 0.f;
#pragma unroll
          for (int k = 0; k < 21; ++k) {
            float a = sal[sl + k];
            fa = fmaf(sdF[q * 21 + k], a, fa);
            ga = fmaf(Gl[q * 21 + k], a, ga);
          }
          f0[q] = fa; g0[q] = ga;
        }
        float acc = 0.f;
        for (int cc = half * 64; cc < half * 64 + 64; ++cc) {
          float a = sdtb[cc];
#pragma unroll
          for (int q = 0; q < 8; ++q)
            a = fmaf(sdU[cc * 8 + q], f0[q], fmaf(sdT[cc * 8 + q], g0[q], a));
          acc = fmaf(sdv[cc], tanhf(a), acc);
        }
        es[sl * 2 + half] = acc;
      }
      __syncthreads();
      // S9a: e = mlp + log(prior)
      if (tid < 512) {
        float pr = 0.f;
#pragma unroll
        for (int k = 0; k < 11; ++k) pr = fmaf(A.pr.v[k], sal[tid + k], pr);
        e[tid] = es[tid * 2] + es[tid * 2 + 1] + logf(fmaxf(pr, 1e-6f));
      }
      __syncthreads();
      // S9b: softmax + compaction + sparse ctx (cached enc, unroll 8)
      {
        int lane = tid & 63, wv = tid >> 6;
        float e0 = (tid < 512) ? e[tid] : -1e30f;
        float m = e0;
        for (int o = 32; o; o >>= 1) m = fmaxf(m, __shfl_xor(m, o));
        if (lane == 0) red[wv] = m;
        __syncthreads();
        m = red[0];
        for (int w = 1; w < 8; ++w) m = fmaxf(m, red[w]);
        float p0 = (tid < 512) ? expf(e0 - m) : 0.f;
        float s = p0;
        for (int o = 32; o; o >>= 1) s += __shfl_xor(s, o);
        __syncthreads();
        if (lane == 0) red[wv] = s;
        __syncthreads();
        float tot = red[0];
        for (int w = 1; w < 8; ++w) tot += red[w];
        float inv = 1.f / tot;
        float a0 = p0 * inv;
        if (tid < 512) alpha[tid] = a0;
        unsigned long long mk = __ballot(tid < 512 && a0 > EPS_A);
        if (lane == 0 && wv < 8) wc[wv] = (int)__popcll(mk);
        __syncthreads();
        int base = 0;
        for (int w = 0; w < wv && w < 8; ++w) base += wc[w];
        int n = 0;
        for (int w = 0; w < 8; ++w) n += wc[w];
        unsigned long long below = (1ull << lane) - 1ull;
        if (tid < 512 && a0 > EPS_A) {
          int pp = base + (int)__popcll(mk & below);
          li[pp] = (short)tid; lv[pp] = a0;
        }
        __syncthreads();
        const float* encb = A.enc + (size_t)b * 512 * 768;
        if (tid < 768) {
          float acc0 = 0.f, acc1 = 0.f;
          int i = 0;
          for (; i + 8 <= n; i += 8) {
            acc0 = fmaf(lv[i],   encb[(size_t)li[i]   * 768 + tid],
                   fmaf(lv[i+1], encb[(size_t)li[i+1] * 768 + tid],
                   fmaf(lv[i+2], encb[(size_t)li[i+2] * 768 + tid],
                   fmaf(lv[i+3], encb[(size_t)li[i+3] * 768 + tid], acc0))));
            acc1 = fmaf(lv[i+4], encb[(size_t)li[i+4] * 768 + tid],
                   fmaf(lv[i+5], encb[(size_t)li[i+5] * 768 + tid],
                   fmaf(lv[i+6], encb[(size_t)li[i+6] * 768 + tid],
                   fmaf(lv[i+7], encb[(size_t)li[i+7] * 768 + tid], acc1))));
          }
          for (; i < n; ++i) acc0 = fmaf(lv[i], encb[(size_t)li[i] * 768 + tid], acc0);
          float acc = acc0 + acc1;
          xcat[tid] = acc;
          gst(ws + B_CTX(p) + b * 768 + tid, acc);
        }
      }
      postw(fl, 0, (unsigned)(t + 1));
      // S10: x = lw @ [ctx; hatt] + lb  N=256 K=1024, 4 parts x 32 groups
      {
        int part = tid >> 8, j = tid & 255;
        const float4* xr = (const float4*)xcat;
        float a = 0.f;
#pragma unroll 16
        for (int g = 0; g < 32; ++g) {
          int gg = part * 32 + g;
          uint4 w = *(const uint4*)(wb + OLW + (size_t)gg * 2048 + j * 8);
          a += dot8(w, xr[gg * 2], xr[gg * 2 + 1]);
        }
        pt[part * 260 + j] = a;
      }
      __syncthreads();
      if (tid < 256) xl[tid] = pt[tid] + pt[260 + tid] + pt[520 + tid] + pt[780 + tid] + A.lb[tid];
      __syncthreads();
      // S11: GRU1 (g1wi k8; gh1 from WH1 helper)
      {
        float giv = 0.f;
        if (tid < 768) {
          const float4* xr = (const float4*)xl;
          float a = 0.f;
#pragma unroll 16
          for (int g = 0; g < 32; ++g) {
            uint4 w = *(const uint4*)(wb + OG1I + (size_t)g * 6144 + tid * 8);
            a += dot8(w, xr[g * 2], xr[g * 2 + 1]);
          }
          giv = a;
        } else if (tid < 776) {
          pollge<1>(fl, NB_WH1 + (tid - 768), 0, (unsigned)(t + 1));
        }
        __syncthreads();
        if (tid < 768) {
          sgi[tid] = giv + A.g1bi[tid];
          sgh[tid] = gld(ws + B_GH1(p) + b * 768 + tid);   // helper added g1bh
        }
        __syncthreads();
        if (tid < 256) {
          float r = sigm(sgi[tid] + sgh[tid]);
          float z = sigm(sgi[256 + tid] + sgh[256 + tid]);
          float n = tanhf(sgi[512 + tid] + r * sgh[512 + tid]);
          float hnew = (1.f - z) * n + z * h1l[tid];
          h1l[tid] = hnew;
          gst(ws + B_H1(p) + b * 256 + tid, hnew);
          x2l[tid] = xl[tid] + hnew;
        }
        postw(fl, 2, (unsigned)(t + 1));
      }
      // S12: GRU2
      {
        float giv = 0.f;
        if (tid < 768) {
          const float4* xr = (const float4*)x2l;
          float a = 0.f;
#pragma unroll 16
          for (int g = 0; g < 32; ++g) {
            uint4 w = *(const uint4*)(wb + OG2I + (size_t)g * 6144 + tid * 8);
            a += dot8(w, xr[g * 2], xr[g * 2 + 1]);
          }
          giv = a;
        } else if (tid < 776) {
          pollge<1>(fl, NB_WH2 + (tid - 768), 0, (unsigned)(t + 1));
        }
        __syncthreads();
        if (tid < 768) {
          sgi[tid] = giv + A.g2bi[tid];
          sgh[tid] = gld(ws + B_GH2(p) + b * 768 + tid);
        }
        __syncthreads();
        if (tid < 256) {
          float r = sigm(sgi[tid] + sgh[tid]);
          float z = sigm(sgi[256 + tid] + sgh[256 + tid]);
          float n = tanhf(sgi[512 + tid] + r * sgh[512 + tid]);
          float hnew = (1.f - z) * n + z * h2l[tid];
          h2l[tid] = hnew;
          gst(ws + B_H2(p) + b * 256 + tid, hnew);
          x3l[tid] = x2l[tid] + hnew;
        }
        postw(fl, 3, (unsigned)(t + 1));
      }
      // S13: proj  N=400 K=256, 2 parts x 16 groups (800 threads)
      if (tid < 800) {
        int part = tid >= 400 ? 1 : 0, j = tid - part * 400;
        const float4* xr = (const float4*)x3l;
        float a = 0.f;
#pragma unroll
        for (int g = 0; g < 16; ++g) {
          int gg = part * 16 + g;
          uint4 w = *(const uint4*)(wb + OPR + (size_t)gg * 3200 + j * 8);
          a += dot8(w, xr[gg * 2], xr[gg * 2 + 1]);
        }
        pt[part * 404 + j] = a;
      }
      __syncthreads();
      if (tid < 400) {
        float v = pt[tid] + pt[404 + tid] + A.prb[tid];
        fr[tid] = v;
        gst(A.dout + (size_t)b * 100000 + (tid / 5) * 1250 + t * 5 + (tid % 5), v);
      }
      __syncthreads();
    }
  } else if (blk < NB_GA) {
    // ---- GIC: gic(t) = awi[:, :768] @ ctx(t-1)  (shadow, row-major) ----
    int rb = blk - NB_GIC, bg = rb >> 4, jg = rb & 15;
    int B = bg * 16, R0 = jg * 48;
    float* cl = sm;  // [16][772]
    for (int t = 0; t < TDEC; ++t) {
      const int p = t & 1;
      if (tid < 16) pollge<4>(fl, bg * 16 + tid, 0, (unsigned)t);
      __syncthreads();
      for (int idx = tid; idx < 12288; idx += 1024) {
        int bb = idx / 768, k = idx - bb * 768;
        cl[bb * 772 + k] = gld(ws + B_CTX(p ^ 1) + (B + bb) * 768 + k);
      }
      __syncthreads();
      if (tid < 768) {
        int rr = tid >> 4, bb = tid & 15;
        int row = R0 + rr;
        const uint4* wr = (const uint4*)(wb + OAWI + (size_t)row * 896);
        const float4* xr = (const float4*)(cl + bb * 772);
        float a = 0.f;
#pragma unroll 16
        for (int k4 = 0; k4 < 96; ++k4) a += dot8(wr[k4], xr[2*k4], xr[2*k4+1]);
        gst(ws + B_GIC(p) + (B + bb) * 768 + row, a);
      }
      postw(fl, 0, (unsigned)(t + 1));
    }
  } else if (blk < NB_WH1) {
    // ---- GA: gh(t) = awh @ hatt(t-1)  (shadow) ----
    int rb = blk - NB_GA, bg = rb >> 2, jg = rb & 3;
    int B = bg * 16, R0 = jg * 192;
    float* hl = sm;  // [16][260]
    for (int t = 0; t < TDEC; ++t) {
      const int p = t & 1;
      if (tid < 16) pollge<4>(fl, bg * 16 + tid, 1, (unsigned)t);
      __syncthreads();
      for (int idx = tid; idx < 4096; idx += 1024) {
        int bb = idx >> 8, k = idx & 255;
        hl[bb * 260 + k] = gld(ws + B_HATT(p ^ 1) + (B + bb) * 256 + k);
      }
      __syncthreads();
#pragma unroll
      for (int pass = 0; pass < 3; ++pass) {
        int rr = pass * 64 + (tid >> 4), bb = tid & 15;
        int row = R0 + rr;
        const uint4* wr = (const uint4*)(wb + OAWH + (size_t)row * 256);
        const float4* xr = (const float4*)(hl + bb * 260);
        float a = 0.f;
#pragma unroll 16
        for (int k4 = 0; k4 < 32; ++k4) a += dot8(wr[k4], xr[2*k4], xr[2*k4+1]);
        gst(ws + B_GH(p) + (B + bb) * 768 + row, a);
      }
      postw(fl, 0, (unsigned)(t + 1));
    }
  } else {
    // ---- WH1/WH2: gh{1,2}(t) = g{1,2}wh @ h{1,2}(t-1), all 64 b  (shadow) ----
    const int isW2 = (blk >= NB_WH2);
    const int w = blk - (isW2 ? NB_WH2 : NB_WH1);
    const unsigned OW = isW2 ? OG2H : OG1H;
    const float* bh = isW2 ? A.g2bh : A.g1bh;
    const int hOff0  = isW2 ? B_H2(0)  : B_H1(0);
    const int ghOff0 = isW2 ? B_GH2(0) : B_GH1(0);
    const int word = isW2 ? 3 : 2;
    const int R0 = w * 96;
    float* hl = sm;  // [64][260]
    for (int t = 0; t < TDEC; ++t) {
      const int p = t & 1;
      if (tid < 64) pollge<4>(fl, tid, word, (unsigned)t);
      __syncthreads();
      for (int idx = tid; idx < 16384; idx += 1024) {
        int bb = idx >> 8, k = idx & 255;
        hl[bb * 260 + k] = gld(ws + hOff0 + (p ^ 1) * 16384 + bb * 256 + k);
      }
      __syncthreads();
#pragma unroll
      for (int pass = 0; pass < 6; ++pass) {
        int o = pass * 1024 + tid;
        int bb = o & 63, lr = o >> 6;
        int row = R0 + lr;
        const uint4* wr = (const uint4*)(wb + OW + (size_t)row * 256);
        const float4* xr = (const float4*)(hl + bb * 260);
        float a = 0.f;
#pragma unroll 16
        for (int k4 = 0; k4 < 32; ++k4) a += dot8(wr[k4], xr[2*k4], xr[2*k4+1]);
        gst(ws + ghOff0 + p * 49152 + bb * 768 + row, a + bh[row]);
      }
      postw(fl, 0, (unsigned)(t + 1));
    }
  }
}

// ---------------- host ----------------
extern "C" void kernel_launch(void* const* d_in, const int* in_sizes, int n_in,
                              void* d_out, int out_size, void* d_ws, size_t ws_size,
                              hipStream_t stream) {
  (void)in_sizes; (void)n_in; (void)out_size; (void)ws_size;
  KArgs A;
  A.enc  = (const float*)d_in[0];
  A.p1w  = (const float*)d_in[1];  A.p1b  = (const float*)d_in[2];
  A.p2w  = (const float*)d_in[3];  A.p2b  = (const float*)d_in[4];
  A.awi  = (const float*)d_in[5];  A.abi  = (const float*)d_in[6];
  A.awh  = (const float*)d_in[7];  A.abh  = (const float*)d_in[8];
  A.dWw  = (const float*)d_in[9];  A.dWb  = (const float*)d_in[10];
  A.dVw  = (const float*)d_in[11]; A.dFw  = (const float*)d_in[12];
  A.dUw  = (const float*)d_in[13]; A.dTw  = (const float*)d_in[14];
  A.dTb  = (const float*)d_in[15]; A.dvw  = (const float*)d_in[16];
  A.lw   = (const float*)d_in[17]; A.lb   = (const float*)d_in[18];
  A.g1wi = (const float*)d_in[19]; A.g1bi = (const float*)d_in[20];
  A.g1wh = (const float*)d_in[21]; A.g1bh = (const float*)d_in[22];
  A.g2wi = (const float*)d_in[23]; A.g2bi = (const float*)d_in[24];
  A.g2wh = (const float*)d_in[25]; A.g2bh = (const float*)d_in[26];
  A.prw  = (const float*)d_in[27]; A.prb  = (const float*)d_in[28];
  A.ws   = (float*)d_ws;
  A.dout = (float*)d_out;

  // beta-binomial prior pmf (n=10, a=0.1, b=0.9), flipped
  {
    double aP = 0.1, bP = 0.9;
    double logB0 = lgamma(aP) + lgamma(bP) - lgamma(aP + bP);
    double pm[11];
    for (int k = 0; k <= 10; ++k) {
      double logC = lgamma(11.0) - lgamma(k + 1.0) - lgamma(11.0 - k);
      double logBt = lgamma(k + aP) + lgamma(10.0 - k + bP) - lgamma(10.0 + aP + bP);
      pm[k] = exp(logC + logBt - logB0);
    }
    for (int k = 0; k < 11; ++k) A.pr.v[k] = (float)pm[10 - k];
  }

  CvtArgs C;
  // k8-interleaved (mode 1): {src, dst, N, K, KP, sstr, soff, mode}
  C.s[0]  = {A.p1w,  OP1,   256, 400, 416, 400, 0, 1};
  C.s[1]  = {A.p2w,  OP2,   128, 256, 256, 256, 0, 1};
  C.s[2]  = {A.awi,  OAWIP, 768, 128, 128, 896, 768, 1};
  C.s[3]  = {A.dWw,  ODW,   128, 256, 256, 256, 0, 1};
  C.s[4]  = {A.dVw,  ODV,   168, 128, 128, 128, 0, 1};
  C.s[5]  = {A.lw,   OLW,   256, 1024, 1024, 1024, 0, 1};
  C.s[6]  = {A.g1wi, OG1I,  768, 256, 256, 256, 0, 1};
  C.s[7]  = {A.g2wi, OG2I,  768, 256, 256, 256, 0, 1};
  C.s[8]  = {A.prw,  OPR,   400, 256, 256, 256, 0, 1};
  // row-major (mode 0): N*KP = element count
  C.s[9]  = {A.awi,  OAWI,  768, 896, 896, 896, 0, 0};
  C.s[10] = {A.awh,  OAWH,  768, 256, 256, 256, 0, 0};
  C.s[11] = {A.g1wh, OG1H,  768, 256, 256, 256, 0, 0};
  C.s[12] = {A.g2wh, OG2H,  768, 256, 256, 256, 0, 0};

  k_init<<<256, 256, 0, stream>>>((float*)d_ws);
  k_cvt<<<256, 256, 0, stream>>>(C, (unsigned short*)((float*)d_ws + CVT_OFF));
  k_decode<<<NBLK, 1024, 0, stream>>>(A);
}